// Round 7
// baseline (436.788 us; speedup 1.0000x reference)
//
#include <hip/hip_runtime.h>
#include <hip/hip_bf16.h>
#include <stdint.h>

typedef float f32x4 __attribute__((ext_vector_type(4)));
typedef float fvec4 __attribute__((ext_vector_type(4)));
typedef short bf16x8 __attribute__((ext_vector_type(8)));

#define HALF_K 24576
#define NUMELK 49152
#define BATCH  8192
#define BM 128
#define BN 256
#define BK 64

__device__ __forceinline__ short f2bf(float f) {
  __hip_bfloat16 h = __float2bfloat16(f);
  return __builtin_bit_cast(short, h);
}

__device__ __forceinline__ void gload_lds16(const short* g, short* l) {
  __builtin_amdgcn_global_load_lds(
      (const __attribute__((address_space(1))) unsigned*)g,
      (__attribute__((address_space(3))) unsigned*)l, 16, 0, 0);
}
__device__ __forceinline__ void gload_lds16f(const float* g, float* l) {
  __builtin_amdgcn_global_load_lds(
      (const __attribute__((address_space(1))) unsigned*)g,
      (__attribute__((address_space(3))) unsigned*)l, 16, 0, 0);
}

// ---------------- prep: B pre-tiled + pre-swizzled bf16 ----------------
// Logical B[col][k], col 0..255 over combined-K (col<128: w_aff_W row col;
// col>=128: b_aff_W row col-128 with K-halves swapped).
//   Bprep[KT*16384 + col*64 + ((kc ^ (col&7))<<3) + e],  k = KT*64 + kc*8 + e
__global__ __launch_bounds__(256)
void nnue_prep(const float* __restrict__ wW, const float* __restrict__ bW,
               short* __restrict__ Bprep) {
  int gid = blockIdx.x * 256 + threadIdx.x;   // grid 6144
  int KT  = gid >> 11;
  int rem = gid & 2047;
  int col = rem >> 3;
  int kc  = rem & 7;
  int kg  = KT * 64 + kc * 8;
  const float* src;
  if (col < 128) {
    src = wW + (size_t)col * NUMELK + kg;
  } else {
    int kk = (kg < HALF_K) ? (kg + HALF_K) : (kg - HALF_K);
    src = bW + (size_t)(col - 128) * NUMELK + kk;
  }
  fvec4 v0 = ((const fvec4*)src)[0];
  fvec4 v1 = ((const fvec4*)src)[1];
  bf16x8 o;
  o[0] = f2bf(v0[0]); o[1] = f2bf(v0[1]); o[2] = f2bf(v0[2]); o[3] = f2bf(v0[3]);
  o[4] = f2bf(v1[0]); o[5] = f2bf(v1[1]); o[6] = f2bf(v1[2]); o[7] = f2bf(v1[3]);
  *(bf16x8*)(Bprep + (size_t)KT * 16384 + col * 64 + ((kc ^ (col & 7)) << 3)) = o;
}

// ---------------- main GEMM: [8192 x 49152] x [49152 x 256] ----------------
// 128x256 tile, BK=64, 8 waves (2M x 4N), per-wave 64x64, acc[4][4] (64 VGPR).
// SINGLE-buffered 64KB LDS -> 2 blocks/CU (TLP covers barrier drains, m114).
// A staged as fp32 via global_load_lds with the XOR-swizzle applied to the
// per-lane GLOBAL source address (linear LDS dest, swizzled read side);
// fp32->bf16 conversion happens at fragment-load time (overlaps MFMA).
// Per iter: compute -> sync -> issue A+B DMA -> sync.
__global__ __launch_bounds__(512, 4)
void nnue_gemm(const float* __restrict__ white, const float* __restrict__ black,
               const short* __restrict__ Bprep, float* __restrict__ partial,
               int kchunk, int S) {
  __shared__ float Alds[BM * BK];   // 32 KB fp32, chunk-swizzled via source
  __shared__ short Blds[BN * BK];   // 32 KB bf16, pre-swizzled by prep

  const int t    = threadIdx.x;
  const int lane = t & 63;
  const int wid  = t >> 6;

  // XCD-grouped decode: blocks on one XCD share ks (B chunk L2-resident)
  const int bid = blockIdx.x;          // 64*S blocks
  const int xcd = bid & 7, bi = bid >> 3;
  const int xpk = 8 / S;               // S in {1,2,4,8}
  const int ks  = xcd / xpk;
  const int mt  = (xcd % xpk) * (64 / xpk) + bi;
  const int m0  = mt * BM;
  const int k0  = ks * kchunk;

  f32x4 acc[4][4];
  const f32x4 zero = {0.f, 0.f, 0.f, 0.f};
#pragma unroll
  for (int a = 0; a < 4; ++a)
#pragma unroll
    for (int b = 0; b < 4; ++b) acc[a][b] = zero;

  const int wm = wid >> 2, wn = wid & 3;
  const int l15 = lane & 15, l4 = lane >> 4;
  const int achunk = lane & 15;        // 16B chunk within a 256B row
  const int arsub  = lane >> 4;        // row offset within a 4-row group

  // A DMA: instr (wid,j) stages rows wid*16+j*4 .. +3 (1KB), LDS linear.
  // LDS slot (row, c) holds A[row][c ^ (row&7)] -> source chunk = c ^ (row&7).
  auto issueDMA = [&](int kg) {
    const float* Af; int ka;
    if (kg < HALF_K) { Af = white; ka = kg; } else { Af = black; ka = kg - HALF_K; }
#pragma unroll
    for (int j = 0; j < 4; ++j) {
      int row = wid * 16 + j * 4 + arsub;
      int sc  = achunk ^ (row & 7);
      const float* src = Af + (size_t)(m0 + row) * HALF_K + ka + sc * 4;
      gload_lds16f(src, &Alds[(wid * 4 + j) * 256]);   // wave-uniform dest
    }
    const int KT = kg >> 6;
    const short* bsrc = Bprep + (size_t)KT * 16384 + wid * 2048 + lane * 8;
    short* bdst = &Blds[wid * 2048];
#pragma unroll
    for (int j = 0; j < 4; ++j)
      gload_lds16(bsrc + j * 512, bdst + j * 512);
  };

  auto compute = [&]() {
#pragma unroll
    for (int kstep = 0; kstep < 2; ++kstep) {
      const int kc = kstep * 4 + l4;   // 0..7
      bf16x8 bfr[4];
#pragma unroll
      for (int nf = 0; nf < 4; ++nf) {
        int col = wn * 64 + nf * 16 + l15;
        bfr[nf] = *(const bf16x8*)&Blds[col * 64 + ((kc ^ (col & 7)) << 3)];
      }
#pragma unroll
      for (int mf = 0; mf < 4; ++mf) {
        int r  = wm * 64 + mf * 16 + l15;
        int c1 = (2 * kc) ^ (r & 7);
        fvec4 lo = *(const fvec4*)&Alds[r * 64 + c1 * 4];
        fvec4 hi = *(const fvec4*)&Alds[r * 64 + (c1 ^ 1) * 4];
        bf16x8 af;
        af[0] = f2bf(lo[0]); af[1] = f2bf(lo[1]); af[2] = f2bf(lo[2]); af[3] = f2bf(lo[3]);
        af[4] = f2bf(hi[0]); af[5] = f2bf(hi[1]); af[6] = f2bf(hi[2]); af[7] = f2bf(hi[3]);
#pragma unroll
        for (int nf = 0; nf < 4; ++nf)
          acc[mf][nf] = __builtin_amdgcn_mfma_f32_16x16x32_bf16(af, bfr[nf], acc[mf][nf], 0, 0, 0);
      }
    }
  };

  const int niter = kchunk / BK;

  issueDMA(k0);
  __syncthreads();                       // drain tile 0

  for (int kt = 0; kt < niter; ++kt) {
    compute();
    __syncthreads();                     // readers done
    if (kt + 1 < niter) issueDMA(k0 + (kt + 1) * BK);
    __syncthreads();                     // drain next tile
  }

  // ---- epilogue: C/D layout col=lane&15, row=(lane>>4)*4+r   [m89]
  float* P = partial + ((size_t)ks * BATCH + m0) * 256;
#pragma unroll
  for (int mf = 0; mf < 4; ++mf) {
    int row = wm * 64 + mf * 16 + l4 * 4;
#pragma unroll
    for (int nf = 0; nf < 4; ++nf) {
      int col = wn * 64 + nf * 16 + l15;
#pragma unroll
      for (int rr = 0; rr < 4; ++rr)
        P[(size_t)(row + rr) * 256 + col] = acc[mf][nf][rr];
    }
  }
}

// ---------------- tail: partial-reduce + pov mix + relu + fc0..fc3 ----------------
__global__ __launch_bounds__(256)
void nnue_tail(const float* __restrict__ partial, int S,
               const float* __restrict__ pov,
               const float* __restrict__ waffb, const float* __restrict__ baffb,
               const float* __restrict__ fc0W, const float* __restrict__ fc0b,
               const float* __restrict__ fc1W, const float* __restrict__ fc1b,
               const float* __restrict__ fc2W, const float* __restrict__ fc2b,
               const float* __restrict__ fc3W, const float* __restrict__ fc3b,
               float* __restrict__ out) {
  __shared__ float w0s[32 * 256];   // stored at [(j<<8) | ((k+j)&255)]
  __shared__ float w1s[32 * 32];    // [(j<<5) | ((k+j)&31)]
  __shared__ float w2s[32 * 64];    // [(j<<6) | ((k+j)&63)]
  __shared__ float w3s[96];
  __shared__ float b0s[32], b1s[32], b2s[32];
  __shared__ float base_s[4][256];
  __shared__ float b3s;

  const int t = threadIdx.x;
  for (int i = t; i < 8192; i += 256) { int j = i >> 8, k = i & 255; w0s[(j << 8) | ((k + j) & 255)] = fc0W[i]; }
  for (int i = t; i < 1024; i += 256) { int j = i >> 5, k = i & 31;  w1s[(j << 5) | ((k + j) & 31)]  = fc1W[i]; }
  for (int i = t; i < 2048; i += 256) { int j = i >> 6, k = i & 63;  w2s[(j << 6) | ((k + j) & 63)]  = fc2W[i]; }
  if (t < 96) w3s[t] = fc3W[t];
  if (t < 32) { b0s[t] = fc0b[t]; b1s[t] = fc1b[t]; b2s[t] = fc2b[t]; }
  if (t == 0) b3s = fc3b[0];
  __syncthreads();

  const int wid = t >> 6, lane = t & 63;
  const int m = blockIdx.x * 4 + wid;
  const float pv = pov[m];

  // lane l holds concat[w_,b_] cols 4l..4l+3 (summed over K-splits, +bias)
  float val[4];
  {
    const float* p = partial + (size_t)m * 256 + lane * 4;
    fvec4 a = *(const fvec4*)p;
    for (int s = 1; s < S; ++s) a += *(const fvec4*)(p + (size_t)s * BATCH * 256);
    const int c0 = lane * 4;
#pragma unroll
    for (int j = 0; j < 4; ++j) {
      int c = c0 + j;
      float bias = (c < 128) ? waffb[c] : baffb[c - 128];
      val[j] = a[j] + bias;
    }
  }
#pragma unroll
  for (int j = 0; j < 4; ++j) {
    float other = __shfl(val[j], lane ^ 32, 64);   // partner holds the b_/w_ counterpart
    if (lane < 32) {
      int c = lane * 4 + j;
      float w = val[j], b = other;
      base_s[wid][c]       = fmaxf(pv * w + (1.f - pv) * b, 0.f);
      base_s[wid][c + 128] = fmaxf(pv * b + (1.f - pv) * w, 0.f);
    }
  }
  __syncthreads();

  const int j = lane & 31, half = lane >> 5;
  const float* bs = &base_s[wid][0];

  // fc0: each (j,half) pair sums 128 terms, then combines across halves
  float s0 = 0.f;
  for (int k = 0; k < 128; ++k) {
    int kk = half * 128 + k;
    s0 += bs[kk] * w0s[(j << 8) | ((kk + j) & 255)];
  }
  s0 += __shfl(s0, lane ^ 32, 64);
  float x0 = fmaxf(s0 + b0s[j], 0.f);

  // fc1 (32x32)
  float s1 = 0.f;
  for (int k = 0; k < 32; ++k)
    s1 += __shfl(x0, k, 64) * w1s[(j << 5) | ((k + j) & 31)];
  float x1 = fmaxf(s1 + b1s[j], 0.f);

  // fc2 (32x64), input = [x0, x1]
  float s2 = 0.f;
  for (int k = 0; k < 32; ++k) {
    s2 += __shfl(x0, k, 64) * w2s[(j << 6) | ((k + j) & 63)];
    s2 += __shfl(x1, k, 64) * w2s[(j << 6) | ((k + 32 + j) & 63)];
  }
  float x2 = fmaxf(s2 + b2s[j], 0.f);

  // fc3 (1x96), input = [x0, x1, x2]
  float s3 = 0.f;
  for (int k = 0; k < 32; ++k) {
    s3 += __shfl(x0, k, 64) * w3s[k];
    s3 += __shfl(x1, k, 64) * w3s[32 + k];
    s3 += __shfl(x2, k, 64) * w3s[64 + k];
  }
  if (lane == 0) out[m] = s3 + b3s;
}

extern "C" void kernel_launch(void* const* d_in, const int* in_sizes, int n_in,
                              void* d_out, int out_size, void* d_ws, size_t ws_size,
                              hipStream_t stream) {
  const float* pov   = (const float*)d_in[0];
  const float* white = (const float*)d_in[1];
  const float* black = (const float*)d_in[2];
  const float* wW    = (const float*)d_in[3];
  const float* wb    = (const float*)d_in[4];
  const float* bW    = (const float*)d_in[5];
  const float* bb    = (const float*)d_in[6];
  const float* fc0W  = (const float*)d_in[7];
  const float* fc0b  = (const float*)d_in[8];
  const float* fc1W  = (const float*)d_in[9];
  const float* fc1b  = (const float*)d_in[10];
  const float* fc2W  = (const float*)d_in[11];
  const float* fc2b  = (const float*)d_in[12];
  const float* fc3W  = (const float*)d_in[13];
  const float* fc3b  = (const float*)d_in[14];
  float* out = (float*)d_out;

  short* Bprep = (short*)d_ws;
  const size_t BWS_BYTES = (size_t)256 * NUMELK * 2;      // 25,165,824
  float* partial = (float*)((char*)d_ws + BWS_BYTES);
  const size_t PART1 = (size_t)BATCH * 256 * 4;           // 8,388,608

  int S = 8;                                              // 512 blocks = 2/CU
  if (ws_size < BWS_BYTES + 8 * PART1) S = 4;
  if (ws_size < BWS_BYTES + 4 * PART1) S = 2;
  if (ws_size < BWS_BYTES + 2 * PART1) S = 1;

  nnue_prep<<<dim3(6144), 256, 0, stream>>>(wW, bW, Bprep);
  nnue_gemm<<<dim3(64 * S), 512, 0, stream>>>(white, black, Bprep, partial, NUMELK / S, S);
  nnue_tail<<<dim3(BATCH / 4), 256, 0, stream>>>(partial, S, pov, wb, bb,
      fc0W, fc0b, fc1W, fc1b, fc2W, fc2b, fc3W, fc3b, out);
}